// Round 1
// baseline (5218.003 us; speedup 1.0000x reference)
//
#include <hip/hip_runtime.h>

typedef unsigned int u32;
typedef unsigned short u16;
typedef __attribute__((ext_vector_type(8))) short short8;
typedef __attribute__((ext_vector_type(4))) float floatx4;

#define T_IN 20
#define T_DEC 45
#define BATCH 32768
#define HID 128

__device__ __forceinline__ u16 f2bf(float f){
  u32 u = __float_as_uint(f);
  u = (u + 0x7FFFu + ((u >> 16) & 1u)) >> 16;
  return (u16)u;
}
__device__ __forceinline__ float bf2f(u16 b){ return __uint_as_float(((u32)b) << 16); }
__device__ __forceinline__ float sigm(float x){ return 1.f / (1.f + __expf(-x)); }
__device__ __forceinline__ float tanh_(float x){ float e = __expf(-2.f * x); return (1.f - e) / (1.f + e); }

// ---------------- prep kernels ----------------
// Re-layout 6 (512x128) fp32 weight matrices into MFMA B-fragment order, bf16.
// frag order: elem e = ((nt*4 + c)*64 + L)*8 + j  ->  W[nt*16 + (L&15)][c*32 + (L>>4)*8 + j]
__global__ __launch_bounds__(256) void prep_weights(
    const float* s0, const float* s1, const float* s2,
    const float* s3, const float* s4, const float* s5, u16* dst)
{
  int idx = blockIdx.x * 256 + threadIdx.x;   // 6*65536 total
  int m = idx >> 16, e = idx & 65535;
  const float* src = m==0?s0: m==1?s1: m==2?s2: m==3?s3: m==4?s4: s5;
  int j = e & 7, L = (e >> 3) & 63, c = (e >> 9) & 3, nt = e >> 11;
  int row = nt * 16 + (L & 15);
  int col = c * 32 + ((L >> 4) * 8) + j;
  dst[idx] = f2bf(src[row * 128 + col]);
}

__global__ __launch_bounds__(256) void prep_bias(
    const float* a0,const float* b0,const float* a1,const float* b1,
    const float* a2,const float* b2,const float* a3,const float* b3, float* dst)
{
  int i = blockIdx.x*256 + threadIdx.x;  // 2048
  int l = i >> 9, n = i & 511;
  const float* a = l==0?a0: l==1?a1: l==2?a2: a3;
  const float* b = l==0?b0: l==1?b1: l==2?b2: b3;
  dst[i] = a[n] + b[n];
}

// ---------------- encoder cell ----------------
// Block: 128 samples (8 M-tiles), 4 waves; wave handles 2 M-tiles, all 512 gates.
// gates = A1@W1^T + A2@W2^T + bias + xsmall@Wsm^T ; then LSTM elementwise; h out (frag order bf16).
__global__ __launch_bounds__(256)
void cell_enc(const u16* __restrict__ A1, const u16* __restrict__ W1,
              const u16* __restrict__ A2, const u16* __restrict__ W2,
              const float* __restrict__ xs, int xs_stride,
              const float* __restrict__ Wsm,
              const float* __restrict__ bias,
              float* __restrict__ Cst, int c_valid,
              u16* __restrict__ Hout)
{
  __shared__ uint4 sWv[2][1024];   // 2 x 16KB weight slice buffers (reused as h staging)
  const int tid = threadIdx.x;
  const int lane = tid & 63, wave = tid >> 6;
  const int n4 = lane & 15, q = lane >> 4;
  const int gmt0 = blockIdx.x * 8 + wave * 2;

  // normalize present (A,W) pairs into slots 0..nW-1
  const u16* Asrc[2] = {nullptr, nullptr};
  const u16* Wu[2]   = {nullptr, nullptr};
  int nW = 0;
  if (A1 && W1){ Asrc[nW]=A1; Wu[nW]=W1; nW++; }
  if (A2 && W2){ Asrc[nW]=A2; Wu[nW]=W2; nW++; }

  short8 aF[2][2][4];   // [slot][mtile][kchunk]
  #pragma unroll
  for (int w = 0; w < 2; w++) if (w < nW) {
    #pragma unroll
    for (int mt = 0; mt < 2; mt++)
      #pragma unroll
      for (int c = 0; c < 4; c++)
        aF[w][mt][c] = *(const short8*)(Asrc[w] + (long)((gmt0+mt)*4 + c)*512 + lane*8);
  }

  float xv[2][4][2];
  if (xs) {
    #pragma unroll
    for (int mt = 0; mt < 2; mt++)
      #pragma unroll
      for (int r = 0; r < 4; r++){
        int mg = blockIdx.x*128 + wave*32 + mt*16 + 4*q + r;
        xv[mt][r][0] = xs[(long)mg*xs_stride];
        xv[mt][r][1] = xs[(long)mg*xs_stride + 1];
      }
  }

  floatx4 acc[4][2];
  u32 hst[2][8][2];
  uint4 pre[4];

  auto stageLoad = [&](int u){
    int s = u / nW, w = u - s*nW;
    const u16* Wp = Wu[w];
    #pragma unroll
    for (int g = 0; g < 4; g++)
      pre[g] = *(const uint4*)(Wp + (g*8 + s)*2048 + tid*8);
  };
  auto stageStore = [&](int half){
    #pragma unroll
    for (int g = 0; g < 4; g++) sWv[half][g*256 + tid] = pre[g];
  };
  auto accInit = [&](int s){
    #pragma unroll
    for (int g = 0; g < 4; g++){
      int n = g*128 + s*16 + n4;
      float bb = bias[n];
      float w0 = 0.f, w1 = 0.f;
      if (Wsm){ w0 = Wsm[n*2]; w1 = Wsm[n*2+1]; }
      #pragma unroll
      for (int mt = 0; mt < 2; mt++)
        #pragma unroll
        for (int r = 0; r < 4; r++){
          float v = bb;
          if (xs) v += xv[mt][r][0]*w0 + xv[mt][r][1]*w1;
          acc[g][mt][r] = v;
        }
    }
  };
  auto consume = [&](int half, short8 (&af)[2][4]){
    const u16* base = (const u16*)&sWv[half][0];
    #pragma unroll
    for (int c = 0; c < 4; c++){
      short8 b[4];
      #pragma unroll
      for (int g = 0; g < 4; g++) b[g] = *(const short8*)(base + g*2048 + c*512 + lane*8);
      #pragma unroll
      for (int g = 0; g < 4; g++)
        #pragma unroll
        for (int mt = 0; mt < 2; mt++)
          acc[g][mt] = __builtin_amdgcn_mfma_f32_16x16x32_bf16(af[c? c:0][0]*0 == 0 ? af[0][0] : af[0][0], b[g], acc[g][mt], 0, 0, 0);
    }
  };
  (void)consume; // replaced below by explicit version (keeps compiler happy if unused)

  auto consume2 = [&](int half, short8 (&af)[2][4]){
    const u16* base = (const u16*)&sWv[half][0];
    #pragma unroll
    for (int c = 0; c < 4; c++){
      short8 b[4];
      #pragma unroll
      for (int g = 0; g < 4; g++) b[g] = *(const short8*)(base + g*2048 + c*512 + lane*8);
      #pragma unroll
      for (int g = 0; g < 4; g++)
        #pragma unroll
        for (int mt = 0; mt < 2; mt++)
          acc[g][mt] = __builtin_amdgcn_mfma_f32_16x16x32_bf16(af[mt][c], b[g], acc[g][mt], 0, 0, 0);
    }
  };

  auto elementwise = [&](int s){
    #pragma unroll
    for (int mt = 0; mt < 2; mt++){
      int coff = ((gmt0+mt)*128 + s*16 + n4)*16 + q*4;
      floatx4 cold;
      if (c_valid) cold = *(const floatx4*)(Cst + coff);
      else { cold[0]=0.f; cold[1]=0.f; cold[2]=0.f; cold[3]=0.f; }
      floatx4 cnew;
      u32 p0 = 0, p1 = 0;
      #pragma unroll
      for (int r = 0; r < 4; r++){
        float iv = acc[0][mt][r], fv = acc[1][mt][r];
        float gv = acc[2][mt][r], ov = acc[3][mt][r];
        float cn = sigm(fv)*cold[r] + sigm(iv)*tanh_(gv);
        float hn = sigm(ov)*tanh_(cn);
        cnew[r] = cn;
        u16 hb = f2bf(hn);
        if (r < 2) p0 |= ((u32)hb) << (16*r); else p1 |= ((u32)hb) << (16*(r-2));
      }
      *(floatx4*)(Cst + coff) = cnew;
      hst[mt][s][0] = p0; hst[mt][s][1] = p1;
    }
  };

  int nU = nW * 8;
  if (nU) {
    stageLoad(0); stageStore(0); __syncthreads();
    for (int s = 0; s < 8; s++){
      accInit(s);
      {
        int u = s*nW;
        if (u+1 < nU) stageLoad(u+1);
        consume2(u & 1, aF[0]);
        if (u+1 < nU) stageStore((u+1)&1);
        __syncthreads();
      }
      if (nW == 2){
        int u = s*2 + 1;
        if (u+1 < nU) stageLoad(u+1);
        consume2(u & 1, aF[1]);
        if (u+1 < nU) stageStore((u+1)&1);
        __syncthreads();
      }
      elementwise(s);
    }
  } else {
    for (int s = 0; s < 8; s++){ accInit(s); elementwise(s); }
    __syncthreads();
  }

  // h staging: C/D layout -> fragment order in LDS, then coalesced flush
  u16* sH = (u16*)&sWv[0][0];
  #pragma unroll
  for (int mt = 0; mt < 2; mt++)
    #pragma unroll
    for (int s = 0; s < 8; s++)
      #pragma unroll
      for (int r = 0; r < 4; r++){
        u16 hv = (u16)(hst[mt][s][r>>1] >> (16*(r&1)));
        int k = s*16 + n4;
        int Ll = 4*q + r + 16*((k>>3)&3);
        sH[((wave*2+mt)*4 + (k>>5))*512 + Ll*8 + (n4 & 7)] = hv;
      }
  __syncthreads();
  uint4* Hv = (uint4*)(Hout + (long)blockIdx.x * 16384);
  const uint4* sf = (const uint4*)sWv;
  #pragma unroll
  for (int it = 0; it < 8; it++)
    Hv[it*256 + tid] = sf[it*256 + tid];
}

// ---------------- decoder fused cell ----------------
__global__ __launch_bounds__(256)
void cell_dec(const u16* __restrict__ H0, const u16* __restrict__ W0hh,
              const float* __restrict__ xs, int xs_stride,
              const float* __restrict__ Wih0, const float* __restrict__ bias0,
              float* __restrict__ C0,
              const u16* __restrict__ H1, const u16* __restrict__ W1hh,
              const u16* __restrict__ W1ih,
              const float* __restrict__ bias1, float* __restrict__ C1,
              const float* __restrict__ fcW, const float* __restrict__ fcb,
              float* __restrict__ predOut, float* __restrict__ out, int t)
{
  __shared__ uint4 sWv[2][1024];
  const int tid = threadIdx.x;
  const int lane = tid & 63, wave = tid >> 6;
  const int n4 = lane & 15, q = lane >> 4;
  const int gmt0 = blockIdx.x * 8 + wave * 2;

  short8 aA[2][4], aB[2][4], a2[2][4];
  #pragma unroll
  for (int mt = 0; mt < 2; mt++)
    #pragma unroll
    for (int c = 0; c < 4; c++){
      aA[mt][c] = *(const short8*)(H0 + (long)((gmt0+mt)*4 + c)*512 + lane*8);
      aB[mt][c] = *(const short8*)(H1 + (long)((gmt0+mt)*4 + c)*512 + lane*8);
    }

  float xv[2][4][2];
  #pragma unroll
  for (int mt = 0; mt < 2; mt++)
    #pragma unroll
    for (int r = 0; r < 4; r++){
      int mg = blockIdx.x*128 + wave*32 + mt*16 + 4*q + r;
      xv[mt][r][0] = xs[(long)mg*xs_stride];
      xv[mt][r][1] = xs[(long)mg*xs_stride + 1];
    }

  floatx4 acc[4][2];
  u32 hst[2][8][2];
  uint4 pre[4];

  auto stageLoadW = [&](const u16* Wp, int s){
    #pragma unroll
    for (int g = 0; g < 4; g++)
      pre[g] = *(const uint4*)(Wp + (g*8 + s)*2048 + tid*8);
  };
  auto stageStore = [&](int half){
    #pragma unroll
    for (int g = 0; g < 4; g++) sWv[half][g*256 + tid] = pre[g];
  };
  auto consume = [&](int half, short8 (&af)[2][4]){
    const u16* base = (const u16*)&sWv[half][0];
    #pragma unroll
    for (int c = 0; c < 4; c++){
      short8 b[4];
      #pragma unroll
      for (int g = 0; g < 4; g++) b[g] = *(const short8*)(base + g*2048 + c*512 + lane*8);
      #pragma unroll
      for (int g = 0; g < 4; g++)
        #pragma unroll
        for (int mt = 0; mt < 2; mt++)
          acc[g][mt] = __builtin_amdgcn_mfma_f32_16x16x32_bf16(af[mt][c], b[g], acc[g][mt], 0, 0, 0);
    }
  };
  auto lstmStep = [&](int s, float* Cst, const float* bias, const float* Wsm){
    #pragma unroll
    for (int g = 0; g < 4; g++){
      // nothing: acc already holds matmul; fold bias/x at init instead
      (void)g;
    }
    #pragma unroll
    for (int mt = 0; mt < 2; mt++){
      int coff = ((gmt0+mt)*128 + s*16 + n4)*16 + q*4;
      floatx4 cold = *(const floatx4*)(Cst + coff);
      floatx4 cnew;
      u32 p0 = 0, p1 = 0;
      #pragma unroll
      for (int r = 0; r < 4; r++){
        float iv = acc[0][mt][r], fv = acc[1][mt][r];
        float gv = acc[2][mt][r], ov = acc[3][mt][r];
        float cn = sigm(fv)*cold[r] + sigm(iv)*tanh_(gv);
        float hn = sigm(ov)*tanh_(cn);
        cnew[r] = cn;
        u16 hb = f2bf(hn);
        if (r < 2) p0 |= ((u32)hb) << (16*r); else p1 |= ((u32)hb) << (16*(r-2));
      }
      *(floatx4*)(Cst + coff) = cnew;
      hst[mt][s][0] = p0; hst[mt][s][1] = p1;
    }
    (void)bias; (void)Wsm;
  };
  auto accInit = [&](int s, const float* bias, const float* Wsm, bool useX){
    #pragma unroll
    for (int g = 0; g < 4; g++){
      int n = g*128 + s*16 + n4;
      float bb = bias[n];
      float w0 = 0.f, w1 = 0.f;
      if (useX){ w0 = Wsm[n*2]; w1 = Wsm[n*2+1]; }
      #pragma unroll
      for (int mt = 0; mt < 2; mt++)
        #pragma unroll
        for (int r = 0; r < 4; r++){
          float v = bb;
          if (useX) v += xv[mt][r][0]*w0 + xv[mt][r][1]*w1;
          acc[g][mt][r] = v;
        }
    }
  };
  auto stashToLDSandFlush = [&](u16* Hdst){
    u16* sH = (u16*)&sWv[0][0];
    #pragma unroll
    for (int mt = 0; mt < 2; mt++)
      #pragma unroll
      for (int s = 0; s < 8; s++)
        #pragma unroll
        for (int r = 0; r < 4; r++){
          u16 hv = (u16)(hst[mt][s][r>>1] >> (16*(r&1)));
          int k = s*16 + n4;
          int Ll = 4*q + r + 16*((k>>3)&3);
          sH[((wave*2+mt)*4 + (k>>5))*512 + Ll*8 + (n4 & 7)] = hv;
        }
    __syncthreads();
    uint4* Hv = (uint4*)(Hdst + (long)blockIdx.x * 16384);
    const uint4* sf = (const uint4*)sWv;
    #pragma unroll
    for (int it = 0; it < 8; it++)
      Hv[it*256 + tid] = sf[it*256 + tid];
  };

  // ---- cell 0 (K=128, x = pred via fp32 path) ----
  stageLoadW(W0hh, 0); stageStore(0); __syncthreads();
  for (int s = 0; s < 8; s++){
    accInit(s, bias0, Wih0, true);
    if (s < 7) stageLoadW(W0hh, s+1);
    consume(s & 1, aA);
    if (s < 7) stageStore((s+1)&1);
    __syncthreads();
    lstmStep(s, C0, bias0, Wih0);
  }
  __syncthreads();
  stashToLDSandFlush((u16*)H0);     // h0_new -> global (for next launch)
  // read h0_new as A-fragments for cell1
  {
    u16* sH = (u16*)&sWv[0][0];
    #pragma unroll
    for (int mt = 0; mt < 2; mt++)
      #pragma unroll
      for (int c = 0; c < 4; c++)
        a2[mt][c] = *(const short8*)(sH + ((wave*2+mt)*4 + c)*512 + lane*8);
  }
  __syncthreads();

  // ---- cell 1 (K=256: [h1 | h0_new]) ----
  stageLoadW(W1hh, 0); stageStore(0); __syncthreads();
  for (int s = 0; s < 8; s++){
    accInit(s, bias1, nullptr, false);
    {
      int u = 2*s;
      stageLoadW(W1ih, s);           // next unit u+1
      consume(u & 1, aB);
      stageStore((u+1)&1);
      __syncthreads();
    }
    {
      int u = 2*s + 1;
      if (s < 7) stageLoadW(W1hh, s+1);
      consume(u & 1, a2);
      if (s < 7) stageStore((u+1)&1);
      __syncthreads();
    }
    lstmStep(s, C1, bias1, nullptr);
  }
  __syncthreads();
  stashToLDSandFlush((u16*)H1);     // h1_new -> global

  // ---- fc head (fp32, in-register + 16-lane butterfly over n4) ----
  float p[2][4][2];
  #pragma unroll
  for (int mt = 0; mt < 2; mt++)
    #pragma unroll
    for (int r = 0; r < 4; r++){ p[mt][r][0] = 0.f; p[mt][r][1] = 0.f; }
  #pragma unroll
  for (int s = 0; s < 8; s++){
    int k = s*16 + n4;
    float w0 = fcW[k], w1 = fcW[128 + k];
    #pragma unroll
    for (int mt = 0; mt < 2; mt++)
      #pragma unroll
      for (int r = 0; r < 4; r++){
        float hv = bf2f((u16)(hst[mt][s][r>>1] >> (16*(r&1))));
        p[mt][r][0] += hv * w0;
        p[mt][r][1] += hv * w1;
      }
  }
  #pragma unroll
  for (int off = 1; off < 16; off <<= 1)
    #pragma unroll
    for (int mt = 0; mt < 2; mt++)
      #pragma unroll
      for (int r = 0; r < 4; r++){
        p[mt][r][0] += __shfl_xor(p[mt][r][0], off, 16);
        p[mt][r][1] += __shfl_xor(p[mt][r][1], off, 16);
      }
  if (n4 == 0){
    #pragma unroll
    for (int mt = 0; mt < 2; mt++)
      #pragma unroll
      for (int r = 0; r < 4; r++){
        int mg = blockIdx.x*128 + wave*32 + mt*16 + 4*q + r;
        #pragma unroll
        for (int j = 0; j < 2; j++){
          float v = p[mt][r][j] + fcb[j];
          predOut[(long)mg*2 + j] = v;
          out[(long)mg*(2*T_DEC) + t*2 + j] = v;
        }
      }
  }
}

// ---------------- host ----------------
extern "C" void kernel_launch(void* const* d_in, const int* in_sizes, int n_in,
                              void* d_out, int out_size, void* d_ws, size_t ws_size,
                              hipStream_t stream)
{
  const float* in_seq = (const float*)d_in[0];
  const float* eWih0 = (const float*)d_in[1];
  const float* eWhh0 = (const float*)d_in[2];
  const float* ebih0 = (const float*)d_in[3];
  const float* ebhh0 = (const float*)d_in[4];
  const float* eWih1 = (const float*)d_in[5];
  const float* eWhh1 = (const float*)d_in[6];
  const float* ebih1 = (const float*)d_in[7];
  const float* ebhh1 = (const float*)d_in[8];
  const float* dWih0 = (const float*)d_in[9];
  const float* dWhh0 = (const float*)d_in[10];
  const float* dbih0 = (const float*)d_in[11];
  const float* dbhh0 = (const float*)d_in[12];
  const float* dWih1 = (const float*)d_in[13];
  const float* dWhh1 = (const float*)d_in[14];
  const float* dbih1 = (const float*)d_in[15];
  const float* dbhh1 = (const float*)d_in[16];
  const float* fcW   = (const float*)d_in[17];
  const float* fcb   = (const float*)d_in[18];
  float* out = (float*)d_out;
  char* ws = (char*)d_ws;

  u16* wAll  = (u16*)(ws + 0);                 // 6 x 128KB frag-order bf16
  u16* wE0hh = (u16*)(ws + 0);
  u16* wE1hh = (u16*)(ws + 131072);
  u16* wE1ih = (u16*)(ws + 262144);
  u16* wD0hh = (u16*)(ws + 393216);
  u16* wD1hh = (u16*)(ws + 524288);
  u16* wD1ih = (u16*)(ws + 655360);
  float* biasAll = (float*)(ws + 786432);      // 4 x 512 fp32
  float* bE0 = biasAll, *bE1 = biasAll+512, *bD0 = biasAll+1024, *bD1 = biasAll+1536;
  u16* ys0  = (u16*)(ws + 1048576);            // 20 slabs x 8MB (frag-order bf16)
  const long SLAB = 4194304;                    // ushorts per slab
  u16* h1b  = (u16*)(ws + 1048576 + 20L*8388608);
  float* c0 = (float*)(ws + 1048576 + 21L*8388608);
  float* c1 = c0 + 4194304;
  float* pred = c1 + 4194304;

  hipLaunchKernelGGL(prep_weights, dim3(1536), dim3(256), 0, stream,
                     eWhh0, eWhh1, eWih1, dWhh0, dWhh1, dWih1, wAll);
  hipLaunchKernelGGL(prep_bias, dim3(8), dim3(256), 0, stream,
                     ebih0, ebhh0, ebih1, ebhh1, dbih0, dbhh0, dbih1, dbhh1, biasAll);

  // encoder layer 0: x_t = input_seq[:, t, :], h chain through ys0 slabs
  for (int t = 0; t < T_IN; t++){
    const u16* Ain = t ? (const u16*)(ys0 + (long)(t-1)*SLAB) : (const u16*)nullptr;
    hipLaunchKernelGGL(cell_enc, dim3(256), dim3(256), 0, stream,
        Ain, (const u16*)wE0hh, (const u16*)nullptr, (const u16*)nullptr,
        in_seq + t*2, 40, eWih0, (const float*)bE0, c0, t ? 1 : 0,
        ys0 + (long)t*SLAB);
  }
  // encoder layer 1: x_t = ys0[t] (K=256 concat), h in-place in h1b
  for (int t = 0; t < T_IN; t++){
    const u16* Ain = t ? (const u16*)h1b : (const u16*)nullptr;
    hipLaunchKernelGGL(cell_enc, dim3(256), dim3(256), 0, stream,
        Ain, (const u16*)wE1hh, (const u16*)(ys0 + (long)t*SLAB), (const u16*)wE1ih,
        (const float*)nullptr, 0, (const float*)nullptr, (const float*)bE1, c1, t ? 1 : 0,
        h1b);
  }
  // decoder: h0 state lives in ys0[19] slab (enc l0 final), h1 in h1b, c's continue
  u16* h0d = ys0 + 19L*SLAB;
  for (int t = 0; t < T_DEC; t++){
    const float* xsp = t ? (const float*)pred : in_seq + 38;
    hipLaunchKernelGGL(cell_dec, dim3(256), dim3(256), 0, stream,
        (const u16*)h0d, (const u16*)wD0hh, xsp, t ? 2 : 40,
        dWih0, (const float*)bD0, c0,
        (const u16*)h1b, (const u16*)wD1hh, (const u16*)wD1ih,
        (const float*)bD1, c1, fcW, fcb, pred, out, t);
  }
}

// Round 2
// 4999.163 us; speedup vs baseline: 1.0438x; 1.0438x over previous
//
#include <hip/hip_runtime.h>

typedef unsigned int u32;
typedef unsigned short u16;
typedef __attribute__((ext_vector_type(8))) short short8;
typedef __attribute__((ext_vector_type(4))) float floatx4;

__device__ __forceinline__ u16 f2bf(float f){
  u32 u = __float_as_uint(f);
  u = (u + 0x7FFFu + ((u >> 16) & 1u)) >> 16;
  return (u16)u;
}
__device__ __forceinline__ float bf2f(u16 b){ return __uint_as_float(((u32)b) << 16); }
__device__ __forceinline__ float sigm(float x){ return 1.f / (1.f + __expf(-x)); }
__device__ __forceinline__ float tanh_(float x){ float e = __expf(-2.f*x); return (1.f-e)/(1.f+e); }

// ---------------- prep: weights -> slice-major MFMA B-fragment order, bf16 ----
// dst[(((s*4+g)*4)+c)*512 + L*8 + j] = W[g*128 + s*16 + (L&15)][c*32 + (L>>4)*8 + j]
// so wave w's slice (units [w*16,w*16+16) of all 4 gates) is 16KB contiguous at w*8192.
__global__ __launch_bounds__(256) void prep_weights(
    const float* s0, const float* s1, const float* s2,
    const float* s3, const float* s4, const float* s5, u16* dst)
{
  int idx = blockIdx.x * 256 + threadIdx.x;   // 6*65536 total
  int m = idx >> 16, e = idx & 65535;
  const float* src = m==0?s0: m==1?s1: m==2?s2: m==3?s3: m==4?s4: s5;
  int j = e & 7, L = (e >> 3) & 63, c = (e >> 9) & 3, g = (e >> 11) & 3, s = (e >> 13) & 7;
  int row = g*128 + s*16 + (L & 15);
  int col = c*32 + ((L >> 4) * 8) + j;
  dst[idx] = f2bf(src[row * 128 + col]);
}

__global__ __launch_bounds__(256) void prep_bias(
    const float* a0,const float* b0,const float* a1,const float* b1,
    const float* a2,const float* b2,const float* a3,const float* b3, float* dst)
{
  int i = blockIdx.x*256 + threadIdx.x;  // 2048
  int l = i >> 9, n = i & 511;
  const float* a = l==0?a0: l==1?a1: l==2?a2: a3;
  const float* b = l==0?b0: l==1?b1: l==2?b2: b3;
  dst[i] = a[n] + b[n];
}

// ---------------- persistent full-network kernel ----------------
// 256 blocks x 512 threads. Block owns 128 samples; wave w owns hidden units
// [w*16, w*16+16) of all 4 gates (its weight slices pinned in VGPRs).
// c-state in VGPRs for the whole run; h round-trips through LDS A-frag slabs.
__global__ __launch_bounds__(512, 2) void lstm_all(
    const float* __restrict__ in_seq,
    const u16* __restrict__ wE0, const u16* __restrict__ wE1h, const u16* __restrict__ wE1x,
    const u16* __restrict__ wD0, const u16* __restrict__ wD1h, const u16* __restrict__ wD1x,
    const float* __restrict__ biasArr,          // [E0|E1|D0|D1] x 512
    const float* __restrict__ eWih0, const float* __restrict__ dWih0,
    const float* __restrict__ fcW, const float* __restrict__ fcb,
    float* __restrict__ predws, float* __restrict__ out)
{
  __shared__ u16 h0s[16384];   // 32KB: h0 in A-frag layout (8 mtiles x 2048)
  __shared__ u16 h1s[16384];   // 32KB: h1
  const int tid  = threadIdx.x;
  const int lane = tid & 63, w = tid >> 6;
  const int n4 = lane & 15, q = lane >> 4;
  const int m0 = blockIdx.x * 128;

  { u32* z0 = (u32*)h0s; u32* z1 = (u32*)h1s;
    for (int i = tid; i < 8192; i += 512){ z0[i] = 0u; z1[i] = 0u; } }

  short8 B0[4][4], B1[4][4], Bx[4][4];     // pinned weight slices (96 VGPRs)
  float b0v[4], b1v[4], wxv[4][2];
  floatx4 c0[8], c1[8];
  const floatx4 z4 = {0.f, 0.f, 0.f, 0.f};
  #pragma unroll
  for (int mt = 0; mt < 8; mt++){ c0[mt] = z4; c1[mt] = z4; }

  auto loadB = [&](short8 (&B)[4][4], const u16* p){
    #pragma unroll
    for (int g = 0; g < 4; g++)
      #pragma unroll
      for (int c = 0; c < 4; c++)
        B[g][c] = *(const short8*)(p + (g*4 + c)*512 + lane*8);
  };
  auto loadConsts = [&](int phase){
    const float* b  = biasArr + phase*1024;
    const float* wx = phase ? dWih0 : eWih0;
    #pragma unroll
    for (int g = 0; g < 4; g++){
      int n = g*128 + w*16 + n4;
      b0v[g] = b[n]; b1v[g] = b[512 + n];
      wxv[g][0] = wx[n*2]; wxv[g][1] = wx[n*2 + 1];
    }
  };
  loadB(B0, wE0 + w*8192); loadB(B1, wE1h + w*8192); loadB(Bx, wE1x + w*8192);
  loadConsts(0);
  __syncthreads();

  // h-write address pieces: value (m = mt*16+4q+r, k = w*16+n4) lands at
  // A-frag offset (mt*4 + (k>>5))*512 + (((k>>3)&3)*16 + (m&15))*8 + (k&7)
  const int cw    = w >> 1;
  const int lbase = ((w & 1)*2 + (n4 >> 3)) * 16;
  const int jw    = n4 & 7;

  #pragma unroll 1
  for (int t = 0; t < 65; t++){
    const bool dec = (t >= 20);
    if (t == 20){
      loadB(B0, wD0 + w*8192); loadB(B1, wD1h + w*8192); loadB(Bx, wD1x + w*8192);
      loadConsts(1);
    }

    // ---------------- cell 0: gates = h0@W0hh^T + x@Wih^T + b ----------------
    float2 xc[4], xn[4];
    #pragma unroll
    for (int r = 0; r < 4; r++){
      int mm = m0 + 4*q + r;
      xc[r] = dec ? (t == 20 ? *(const float2*)(in_seq + mm*40 + 38)
                             : *(const float2*)(predws + mm*2))
                  : *(const float2*)(in_seq + mm*40 + t*2);
    }
    #pragma unroll 1
    for (int mt = 0; mt < 8; mt++){
      short8 a[4];
      #pragma unroll
      for (int c = 0; c < 4; c++)
        a[c] = *(const short8*)(h0s + (mt*4 + c)*512 + lane*8);
      if (mt < 7){
        #pragma unroll
        for (int r = 0; r < 4; r++){
          int mm = m0 + (mt+1)*16 + 4*q + r;
          xn[r] = dec ? (t == 20 ? *(const float2*)(in_seq + mm*40 + 38)
                                 : *(const float2*)(predws + mm*2))
                      : *(const float2*)(in_seq + mm*40 + t*2);
        }
      }
      __syncthreads();   // all waves done reading h0s(mt) -> in-place write safe
      floatx4 acc[4];
      #pragma unroll
      for (int g = 0; g < 4; g++)
        #pragma unroll
        for (int r = 0; r < 4; r++)
          acc[g][r] = b0v[g] + xc[r].x * wxv[g][0] + xc[r].y * wxv[g][1];
      #pragma unroll
      for (int c = 0; c < 4; c++)
        #pragma unroll
        for (int g = 0; g < 4; g++)
          acc[g] = __builtin_amdgcn_mfma_f32_16x16x32_bf16(a[c], B0[g][c], acc[g], 0, 0, 0);
      floatx4 cc = c0[mt], cn;
      #pragma unroll
      for (int r = 0; r < 4; r++){
        float cv = sigm(acc[1][r]) * cc[r] + sigm(acc[0][r]) * tanh_(acc[2][r]);
        float hv = sigm(acc[3][r]) * tanh_(cv);
        cn[r] = cv;
        h0s[(mt*4 + cw)*512 + (lbase + 4*q + r)*8 + jw] = f2bf(hv);
      }
      c0[mt] = cn;
      if (mt < 7){
        #pragma unroll
        for (int r = 0; r < 4; r++) xc[r] = xn[r];
      }
    }

    // ---------------- cell 1: gates = h1@W1hh^T + h0new@W1ih^T + b ----------
    #pragma unroll 1
    for (int mt = 0; mt < 8; mt++){
      short8 a1[4], a0[4];
      #pragma unroll
      for (int c = 0; c < 4; c++){
        a1[c] = *(const short8*)(h1s + (mt*4 + c)*512 + lane*8);
        a0[c] = *(const short8*)(h0s + (mt*4 + c)*512 + lane*8);
      }
      __syncthreads();   // all waves done reading h1s(mt) -> in-place write safe
      floatx4 acc[4];
      #pragma unroll
      for (int g = 0; g < 4; g++)
        #pragma unroll
        for (int r = 0; r < 4; r++)
          acc[g][r] = b1v[g];
      #pragma unroll
      for (int c = 0; c < 4; c++)
        #pragma unroll
        for (int g = 0; g < 4; g++){
          acc[g] = __builtin_amdgcn_mfma_f32_16x16x32_bf16(a1[c], B1[g][c], acc[g], 0, 0, 0);
          acc[g] = __builtin_amdgcn_mfma_f32_16x16x32_bf16(a0[c], Bx[g][c], acc[g], 0, 0, 0);
        }
      floatx4 cc = c1[mt], cn;
      #pragma unroll
      for (int r = 0; r < 4; r++){
        float cv = sigm(acc[1][r]) * cc[r] + sigm(acc[0][r]) * tanh_(acc[2][r]);
        float hv = sigm(acc[3][r]) * tanh_(cv);
        cn[r] = cv;
        h1s[(mt*4 + cw)*512 + (lbase + 4*q + r)*8 + jw] = f2bf(hv);
      }
      c1[mt] = cn;
    }
    __syncthreads();   // h1 complete before FC reads

    // ---------------- FC head (decoder only): pred = h1@fcW^T + fcb ----------
    if (dec){
      short8 af[4];
      #pragma unroll
      for (int c = 0; c < 4; c++)
        af[c] = *(const short8*)(h1s + (w*4 + c)*512 + lane*8);
      float p0 = 0.f, p1 = 0.f;
      #pragma unroll
      for (int c = 0; c < 4; c++){
        const float* w0 = fcW + c*32 + q*8;
        const float* w1 = w0 + 128;
        #pragma unroll
        for (int jj = 0; jj < 8; jj++){
          float hv = bf2f((u16)af[c][jj]);
          p0 += hv * w0[jj];
          p1 += hv * w1[jj];
        }
      }
      p0 += __shfl_xor(p0, 16); p0 += __shfl_xor(p0, 32);
      p1 += __shfl_xor(p1, 16); p1 += __shfl_xor(p1, 32);
      if (lane < 16){
        int mm = m0 + w*16 + lane;
        float2 pv; pv.x = p0 + fcb[0]; pv.y = p1 + fcb[1];
        *(float2*)(predws + mm*2) = pv;
        *(float2*)(out + (long)mm*90 + (t - 20)*2) = pv;
      }
    }
    __syncthreads();   // pred visible (vmcnt drained) before next step's prefetch
  }
}

// ---------------- host ----------------
extern "C" void kernel_launch(void* const* d_in, const int* in_sizes, int n_in,
                              void* d_out, int out_size, void* d_ws, size_t ws_size,
                              hipStream_t stream)
{
  const float* in_seq = (const float*)d_in[0];
  const float* eWih0 = (const float*)d_in[1];
  const float* eWhh0 = (const float*)d_in[2];
  const float* ebih0 = (const float*)d_in[3];
  const float* ebhh0 = (const float*)d_in[4];
  const float* eWih1 = (const float*)d_in[5];
  const float* eWhh1 = (const float*)d_in[6];
  const float* ebih1 = (const float*)d_in[7];
  const float* ebhh1 = (const float*)d_in[8];
  const float* dWih0 = (const float*)d_in[9];
  const float* dWhh0 = (const float*)d_in[10];
  const float* dbih0 = (const float*)d_in[11];
  const float* dbhh0 = (const float*)d_in[12];
  const float* dWih1 = (const float*)d_in[13];
  const float* dWhh1 = (const float*)d_in[14];
  const float* dbih1 = (const float*)d_in[15];
  const float* dbhh1 = (const float*)d_in[16];
  const float* fcW   = (const float*)d_in[17];
  const float* fcb   = (const float*)d_in[18];
  float* out = (float*)d_out;
  char* ws = (char*)d_ws;

  u16* wAll  = (u16*)(ws + 0);                 // 6 x 128KB slice-major bf16
  u16* wE0   = (u16*)(ws + 0);
  u16* wE1h  = (u16*)(ws + 131072);
  u16* wE1x  = (u16*)(ws + 262144);
  u16* wD0   = (u16*)(ws + 393216);
  u16* wD1h  = (u16*)(ws + 524288);
  u16* wD1x  = (u16*)(ws + 655360);
  float* biasAll = (float*)(ws + 786432);      // 4 x 512 fp32
  float* predws  = (float*)(ws + 1048576);     // 32768 x 2 fp32

  hipLaunchKernelGGL(prep_weights, dim3(1536), dim3(256), 0, stream,
                     eWhh0, eWhh1, eWih1, dWhh0, dWhh1, dWih1, wAll);
  hipLaunchKernelGGL(prep_bias, dim3(8), dim3(256), 0, stream,
                     ebih0, ebhh0, ebih1, ebhh1, dbih0, dbhh0, dbih1, dbhh1, biasAll);

  hipLaunchKernelGGL(lstm_all, dim3(256), dim3(512), 0, stream,
                     in_seq,
                     (const u16*)wE0, (const u16*)wE1h, (const u16*)wE1x,
                     (const u16*)wD0, (const u16*)wD1h, (const u16*)wD1x,
                     (const float*)biasAll, eWih0, dWih0, fcW, fcb,
                     predws, out);
}

// Round 5
// 2079.065 us; speedup vs baseline: 2.5098x; 2.4045x over previous
//
#include <hip/hip_runtime.h>

typedef unsigned int u32;
typedef unsigned short u16;
typedef __attribute__((ext_vector_type(8))) short short8;
typedef __attribute__((ext_vector_type(4))) float floatx4;

#define L2E  1.44269504088896340736f
#define L2E2 2.88539008177792681472f

static __device__ __forceinline__ u16 f2bf(float f){
  u32 u = __float_as_uint(f);
  u = (u + 0x7FFFu + ((u >> 16) & 1u)) >> 16;
  return (u16)u;
}
static __device__ __forceinline__ float rcp_(float x){ return __builtin_amdgcn_rcpf(x); }
static __device__ __forceinline__ float exp2_(float x){ return __builtin_amdgcn_exp2f(x); }
static __device__ __forceinline__ float sigm2(float yh){ return rcp_(1.f + exp2_(-yh)); }   // log2e folded
static __device__ __forceinline__ float tanh2(float yh2){ return 1.f - 2.f*rcp_(1.f + exp2_(yh2)); } // 2*log2e folded

// ---- prep: weights -> slice-major MFMA B-frag order, bf16, log2e-prescaled ----
// (validated: round 3 call-1 absmax 4.9e-4)
__global__ __launch_bounds__(256) void prep_weights(
    const float* eWhh0, const float* eWhh1, const float* eWih1,
    const float* dWhh0, const float* dWhh1, const float* dWih1,
    u16* wE0, u16* wE1, u16* wD0, u16* wD1)
{
  int idx = blockIdx.x * 256 + threadIdx.x;   // 6*65536
  int m = idx >> 16, e = idx & 65535;
  int j = e & 7, L = (e >> 3) & 63, c = (e >> 9) & 3, g = (e >> 11) & 3, s = (e >> 13) & 7;
  int row = g*128 + s*16 + (L & 15);
  int col = c*32 + ((L >> 4) * 8) + j;
  float scale = (g == 2) ? L2E2 : L2E;
  int frag = (g*4 + c)*512 + L*8 + j;
  const float* src; u16* dst; long off;
  switch(m){
    case 0: src = eWhh0; dst = wE0; off = (long)s*8192  + frag; break;
    case 1: src = eWhh1; dst = wE1; off = (long)s*16384 + frag; break;
    case 2: src = eWih1; dst = wE1; off = (long)s*16384 + 8192 + frag; break;
    case 3: src = dWhh0; dst = wD0; off = (long)s*8192  + frag; break;
    case 4: src = dWhh1; dst = wD1; off = (long)s*16384 + frag; break;
    default:src = dWih1; dst = wD1; off = (long)s*16384 + 8192 + frag; break;
  }
  dst[off] = f2bf(src[row*128 + col] * scale);
}

__global__ __launch_bounds__(256) void prep_small(
    const float* ebih0,const float* ebhh0,const float* ebih1,const float* ebhh1,
    const float* dbih0,const float* dbhh0,const float* dbih1,const float* dbhh1,
    const float* eWih0,const float* dWih0, float* biasAll, float* wxAll)
{
  int i = blockIdx.x*256 + threadIdx.x;    // 4096
  if (i < 2048){
    int l = i >> 9, n = i & 511, g = (n >> 7) & 3;
    const float* a = l==0?ebih0: l==1?ebih1: l==2?dbih0: dbih1;
    const float* b = l==0?ebhh0: l==1?ebhh1: l==2?dbhh0: dbhh1;
    biasAll[i] = (a[n] + b[n]) * ((g==2)? L2E2 : L2E);
  } else {
    int k = i - 2048;                       // 2 x 1024
    int l = k >> 10, e2 = k & 1023, n = e2 >> 1, g = (n >> 7) & 3;
    const float* wsrc = l ? dWih0 : eWih0;
    wxAll[k] = wsrc[e2] * ((g==2)? L2E2 : L2E);
  }
}

// =======================================================================
// Chunked kernels: K=5 time-steps per launch. 256 blocks x 512 threads.
// Wave w (0..7) owns mtile w (16 samples) for both cells; h slabs wave-local
// in LDS within the chunk; c-state in VGPRs within the chunk; h(bf16 A-frag),
// c(fp32) round-trip global at chunk boundaries. Step engine is round-3's
// call-1-validated code, unchanged.
// =======================================================================

__global__ __launch_bounds__(512, 1) void enc_chunk(
    const float* __restrict__ in_seq,
    const u16* __restrict__ wE0, const u16* __restrict__ wE1,
    const float* __restrict__ biasAll, const float* __restrict__ wxAll,
    u16* __restrict__ gH0, u16* __restrict__ gH1,
    float* __restrict__ gC0, float* __restrict__ gC1,
    int t0, int K)
{
  __shared__ u16 h0s[16384];
  __shared__ u16 h1s[16384];
  __shared__ u16 stg[2][16384];
  __shared__ float sB[1024];
  __shared__ float sWx[1024];

  const int tid = threadIdx.x, lane = tid & 63, w = tid >> 6;
  const int n4 = lane & 15, q = lane >> 4;
  const int m0 = blockIdx.x * 128;
  const long hoff = (long)blockIdx.x * 16384;
  const long cbase = (long)blockIdx.x * 512 + tid;

  for (int i = tid; i < 1024; i += 512){ sB[i] = biasAll[i]; sWx[i] = wxAll[i]; }

  floatx4 c0a[8], c1a[8];
  if (t0 == 0){
    u32* z0 = (u32*)h0s; u32* z1 = (u32*)h1s;
    for (int i = tid; i < 8192; i += 512){ z0[i] = 0u; z1[i] = 0u; }
    const floatx4 z4 = {0.f,0.f,0.f,0.f};
    #pragma unroll
    for (int s = 0; s < 8; s++){ c0a[s] = z4; c1a[s] = z4; }
  } else {
    uint4* d0 = (uint4*)h0s; uint4* d1 = (uint4*)h1s;
    const uint4* s0 = (const uint4*)(gH0 + hoff);
    const uint4* s1 = (const uint4*)(gH1 + hoff);
    for (int i = tid; i < 2048; i += 512){ d0[i] = s0[i]; d1[i] = s1[i]; }
    const floatx4* pc0 = (const floatx4*)gC0;
    const floatx4* pc1 = (const floatx4*)gC1;
    #pragma unroll
    for (int s = 0; s < 8; s++){ c0a[s] = pc0[(long)s*131072 + cbase]; c1a[s] = pc1[(long)s*131072 + cbase]; }
  }
  // stage unit 0 (wE0 unit 0) into stg[0]
  { const uint4* s4 = (const uint4*)(wE0 + w*2048);
    uint4* d4 = (uint4*)(stg[0] + w*2048);
    #pragma unroll
    for (int i = 0; i < 4; i++) d4[i*64 + lane] = s4[i*64 + lane]; }
  __syncthreads();

  #pragma unroll 1
  for (int tt = 0; tt < K; tt++){
    const int t = t0 + tt;
    float2 xc[4];
    #pragma unroll
    for (int r = 0; r < 4; r++)
      xc[r] = *(const float2*)(in_seq + (long)(m0 + w*16 + q*4 + r)*40 + t*2);
    short8 ah[4];
    #pragma unroll
    for (int c = 0; c < 4; c++)
      ah[c] = *(const short8*)(h0s + (w*4 + c)*512 + lane*8);

    // ---- cell 0: units 0..3 (2 slices each) ----
    #pragma unroll 1
    for (int u = 0; u < 4; u++){
      const u16* nsrc = (u < 3) ? (wE0 + (u+1)*16384) : wE1;
      uint4 pre[4];
      { const uint4* s4 = (const uint4*)(nsrc + w*2048);
        #pragma unroll
        for (int i = 0; i < 4; i++) pre[i] = s4[i*64 + lane]; }
      const u16* bb = stg[u & 1];
      #pragma unroll
      for (int sl = 0; sl < 2; sl++){
        const int s = u*2 + sl;
        const u16* bs = bb + sl*8192;
        floatx4 acc[4];
        #pragma unroll
        for (int g = 0; g < 4; g++){
          float bi = sB[g*128 + s*16 + n4];
          float2 wv = *(const float2*)(sWx + (g*128 + s*16 + n4)*2);
          #pragma unroll
          for (int r = 0; r < 4; r++)
            acc[g][r] = fmaf(xc[r].y, wv.y, fmaf(xc[r].x, wv.x, bi));
        }
        #pragma unroll
        for (int g = 0; g < 4; g++){
          short8 b0 = *(const short8*)(bs + (g*4+0)*512 + lane*8);
          short8 b1 = *(const short8*)(bs + (g*4+1)*512 + lane*8);
          short8 b2 = *(const short8*)(bs + (g*4+2)*512 + lane*8);
          short8 b3 = *(const short8*)(bs + (g*4+3)*512 + lane*8);
          acc[g] = __builtin_amdgcn_mfma_f32_16x16x32_bf16(ah[0], b0, acc[g], 0,0,0);
          acc[g] = __builtin_amdgcn_mfma_f32_16x16x32_bf16(ah[1], b1, acc[g], 0,0,0);
          acc[g] = __builtin_amdgcn_mfma_f32_16x16x32_bf16(ah[2], b2, acc[g], 0,0,0);
          acc[g] = __builtin_amdgcn_mfma_f32_16x16x32_bf16(ah[3], b3, acc[g], 0,0,0);
        }
        const int hb = (w*4 + (s>>1))*512 + ((s&1)*2 + (n4>>3))*128 + q*32 + (n4&7);
        floatx4 cc = c0a[s], cn;
        #pragma unroll
        for (int r = 0; r < 4; r++){
          float ig = sigm2(acc[0][r]);
          float fg = sigm2(acc[1][r]);
          float gg = tanh2(acc[2][r]);
          float cv = fmaf(fg, cc[r], ig*gg);
          float og = sigm2(acc[3][r]);
          float hv = og * (1.f - 2.f*rcp_(1.f + exp2_(L2E2*cv)));
          cn[r] = cv;
          h0s[hb + r*8] = f2bf(hv);
        }
        c0a[s] = cn;
      }
      { uint4* d4 = (uint4*)(stg[(u+1) & 1] + w*2048);
        #pragma unroll
        for (int i = 0; i < 4; i++) d4[i*64 + lane] = pre[i]; }
      __syncthreads();
    }

    // ---- cell 1: units 4..11 (K=256: [h1_old | h0_new]) ----
    short8 a1[4], an[4];
    #pragma unroll
    for (int c = 0; c < 4; c++){
      a1[c] = *(const short8*)(h1s + (w*4 + c)*512 + lane*8);
      an[c] = *(const short8*)(h0s + (w*4 + c)*512 + lane*8);
    }
    #pragma unroll 1
    for (int u = 4; u < 12; u++){
      const u16* nsrc = (u < 11) ? (wE1 + (long)(u-3)*16384)
                                 : ((tt < K-1) ? wE0 : (const u16*)nullptr);
      uint4 pre[4];
      if (nsrc){
        const uint4* s4 = (const uint4*)(nsrc + w*2048);
        #pragma unroll
        for (int i = 0; i < 4; i++) pre[i] = s4[i*64 + lane];
      }
      const u16* bs = stg[u & 1];
      const int s = u - 4;
      floatx4 acc[4];
      #pragma unroll
      for (int g = 0; g < 4; g++){
        float bi = sB[512 + g*128 + s*16 + n4];
        #pragma unroll
        for (int r = 0; r < 4; r++) acc[g][r] = bi;
      }
      #pragma unroll
      for (int g = 0; g < 4; g++){
        short8 bh0 = *(const short8*)(bs + (g*4+0)*512 + lane*8);
        short8 bh1 = *(const short8*)(bs + (g*4+1)*512 + lane*8);
        short8 bh2 = *(const short8*)(bs + (g*4+2)*512 + lane*8);
        short8 bh3 = *(const short8*)(bs + (g*4+3)*512 + lane*8);
        short8 bx0 = *(const short8*)(bs + 8192 + (g*4+0)*512 + lane*8);
        short8 bx1 = *(const short8*)(bs + 8192 + (g*4+1)*512 + lane*8);
        short8 bx2 = *(const short8*)(bs + 8192 + (g*4+2)*512 + lane*8);
        short8 bx3 = *(const short8*)(bs + 8192 + (g*4+3)*512 + lane*8);
        acc[g] = __builtin_amdgcn_mfma_f32_16x16x32_bf16(a1[0], bh0, acc[g], 0,0,0);
        acc[g] = __builtin_amdgcn_mfma_f32_16x16x32_bf16(an[0], bx0, acc[g], 0,0,0);
        acc[g] = __builtin_amdgcn_mfma_f32_16x16x32_bf16(a1[1], bh1, acc[g], 0,0,0);
        acc[g] = __builtin_amdgcn_mfma_f32_16x16x32_bf16(an[1], bx1, acc[g], 0,0,0);
        acc[g] = __builtin_amdgcn_mfma_f32_16x16x32_bf16(a1[2], bh2, acc[g], 0,0,0);
        acc[g] = __builtin_amdgcn_mfma_f32_16x16x32_bf16(an[2], bx2, acc[g], 0,0,0);
        acc[g] = __builtin_amdgcn_mfma_f32_16x16x32_bf16(a1[3], bh3, acc[g], 0,0,0);
        acc[g] = __builtin_amdgcn_mfma_f32_16x16x32_bf16(an[3], bx3, acc[g], 0,0,0);
      }
      const int hb = (w*4 + (s>>1))*512 + ((s&1)*2 + (n4>>3))*128 + q*32 + (n4&7);
      floatx4 cc = c1a[s], cn;
      #pragma unroll
      for (int r = 0; r < 4; r++){
        float ig = sigm2(acc[0][r]);
        float fg = sigm2(acc[1][r]);
        float gg = tanh2(acc[2][r]);
        float cv = fmaf(fg, cc[r], ig*gg);
        float og = sigm2(acc[3][r]);
        float hv = og * (1.f - 2.f*rcp_(1.f + exp2_(L2E2*cv)));
        cn[r] = cv;
        h1s[hb + r*8] = f2bf(hv);
      }
      c1a[s] = cn;
      if (nsrc){
        uint4* d4 = (uint4*)(stg[(u+1) & 1] + w*2048);
        #pragma unroll
        for (int i = 0; i < 4; i++) d4[i*64 + lane] = pre[i];
      }
      __syncthreads();
    }
  }

  // ---- chunk state flush (last u=11 barrier already ordered h writes) ----
  { const uint4* s0 = (const uint4*)h0s; const uint4* s1 = (const uint4*)h1s;
    uint4* d0 = (uint4*)(gH0 + hoff); uint4* d1 = (uint4*)(gH1 + hoff);
    for (int i = tid; i < 2048; i += 512){ d0[i] = s0[i]; d1[i] = s1[i]; } }
  { floatx4* pc0 = (floatx4*)gC0; floatx4* pc1 = (floatx4*)gC1;
    #pragma unroll
    for (int s = 0; s < 8; s++){ pc0[(long)s*131072 + cbase] = c0a[s]; pc1[(long)s*131072 + cbase] = c1a[s]; } }
}

__global__ __launch_bounds__(512, 1) void dec_chunk(
    const float* __restrict__ in_seq,
    const u16* __restrict__ wD0, const u16* __restrict__ wD1,
    const float* __restrict__ biasD, const float* __restrict__ wxD,
    const float* __restrict__ fcW, const float* __restrict__ fcb,
    u16* __restrict__ gH0, u16* __restrict__ gH1,
    float* __restrict__ gC0, float* __restrict__ gC1,
    float* __restrict__ gPred, float* __restrict__ out,
    int t0, int K, int first)
{
  __shared__ u16 h0s[16384];
  __shared__ u16 h1s[16384];
  __shared__ u16 stg[2][16384];
  __shared__ float sB[1024];
  __shared__ float sWx[1024];
  __shared__ float sFc[260];

  const int tid = threadIdx.x, lane = tid & 63, w = tid >> 6;
  const int n4 = lane & 15, q = lane >> 4;
  const int m0 = blockIdx.x * 128;
  const long hoff = (long)blockIdx.x * 16384;
  const long cbase = (long)blockIdx.x * 512 + tid;

  for (int i = tid; i < 1024; i += 512){ sB[i] = biasD[i]; sWx[i] = wxD[i]; }
  if (tid < 258) sFc[tid] = (tid < 256) ? fcW[tid] : fcb[tid-256];

  floatx4 c0a[8], c1a[8];
  { uint4* d0 = (uint4*)h0s; uint4* d1 = (uint4*)h1s;
    const uint4* s0 = (const uint4*)(gH0 + hoff);
    const uint4* s1 = (const uint4*)(gH1 + hoff);
    for (int i = tid; i < 2048; i += 512){ d0[i] = s0[i]; d1[i] = s1[i]; }
    const floatx4* pc0 = (const floatx4*)gC0;
    const floatx4* pc1 = (const floatx4*)gC1;
    #pragma unroll
    for (int s = 0; s < 8; s++){ c0a[s] = pc0[(long)s*131072 + cbase]; c1a[s] = pc1[(long)s*131072 + cbase]; } }
  { const uint4* s4 = (const uint4*)(wD0 + w*2048);
    uint4* d4 = (uint4*)(stg[0] + w*2048);
    #pragma unroll
    for (int i = 0; i < 4; i++) d4[i*64 + lane] = s4[i*64 + lane]; }

  float2 xc[4];
  #pragma unroll
  for (int r = 0; r < 4; r++){
    const long mm = m0 + w*16 + q*4 + r;
    xc[r] = first ? *(const float2*)(in_seq + mm*40 + 38)
                  : *(const float2*)(gPred + mm*2);
  }
  __syncthreads();

  #pragma unroll 1
  for (int tt = 0; tt < K; tt++){
    const int t = t0 + tt;
    short8 ah[4];
    #pragma unroll
    for (int c = 0; c < 4; c++)
      ah[c] = *(const short8*)(h0s + (w*4 + c)*512 + lane*8);

    // ---- cell 0 ----
    #pragma unroll 1
    for (int u = 0; u < 4; u++){
      const u16* nsrc = (u < 3) ? (wD0 + (u+1)*16384) : wD1;
      uint4 pre[4];
      { const uint4* s4 = (const uint4*)(nsrc + w*2048);
        #pragma unroll
        for (int i = 0; i < 4; i++) pre[i] = s4[i*64 + lane]; }
      const u16* bb = stg[u & 1];
      #pragma unroll
      for (int sl = 0; sl < 2; sl++){
        const int s = u*2 + sl;
        const u16* bs = bb + sl*8192;
        floatx4 acc[4];
        #pragma unroll
        for (int g = 0; g < 4; g++){
          float bi = sB[g*128 + s*16 + n4];
          float2 wv = *(const float2*)(sWx + (g*128 + s*16 + n4)*2);
          #pragma unroll
          for (int r = 0; r < 4; r++)
            acc[g][r] = fmaf(xc[r].y, wv.y, fmaf(xc[r].x, wv.x, bi));
        }
        #pragma unroll
        for (int g = 0; g < 4; g++){
          short8 b0 = *(const short8*)(bs + (g*4+0)*512 + lane*8);
          short8 b1 = *(const short8*)(bs + (g*4+1)*512 + lane*8);
          short8 b2 = *(const short8*)(bs + (g*4+2)*512 + lane*8);
          short8 b3 = *(const short8*)(bs + (g*4+3)*512 + lane*8);
          acc[g] = __builtin_amdgcn_mfma_f32_16x16x32_bf16(ah[0], b0, acc[g], 0,0,0);
          acc[g] = __builtin_amdgcn_mfma_f32_16x16x32_bf16(ah[1], b1, acc[g], 0,0,0);
          acc[g] = __builtin_amdgcn_mfma_f32_16x16x32_bf16(ah[2], b2, acc[g], 0,0,0);
          acc[g] = __builtin_amdgcn_mfma_f32_16x16x32_bf16(ah[3], b3, acc[g], 0,0,0);
        }
        const int hb = (w*4 + (s>>1))*512 + ((s&1)*2 + (n4>>3))*128 + q*32 + (n4&7);
        floatx4 cc = c0a[s], cn;
        #pragma unroll
        for (int r = 0; r < 4; r++){
          float ig = sigm2(acc[0][r]);
          float fg = sigm2(acc[1][r]);
          float gg = tanh2(acc[2][r]);
          float cv = fmaf(fg, cc[r], ig*gg);
          float og = sigm2(acc[3][r]);
          float hv = og * (1.f - 2.f*rcp_(1.f + exp2_(L2E2*cv)));
          cn[r] = cv;
          h0s[hb + r*8] = f2bf(hv);
        }
        c0a[s] = cn;
      }
      { uint4* d4 = (uint4*)(stg[(u+1) & 1] + w*2048);
        #pragma unroll
        for (int i = 0; i < 4; i++) d4[i*64 + lane] = pre[i]; }
      __syncthreads();
    }

    // ---- cell 1 + FC accumulate ----
    short8 a1[4], an[4];
    #pragma unroll
    for (int c = 0; c < 4; c++){
      a1[c] = *(const short8*)(h1s + (w*4 + c)*512 + lane*8);
      an[c] = *(const short8*)(h0s + (w*4 + c)*512 + lane*8);
    }
    float p[4][2];
    #pragma unroll
    for (int r = 0; r < 4; r++){ p[r][0] = 0.f; p[r][1] = 0.f; }

    #pragma unroll 1
    for (int u = 4; u < 12; u++){
      const u16* nsrc = (u < 11) ? (wD1 + (long)(u-3)*16384)
                                 : ((tt < K-1) ? wD0 : (const u16*)nullptr);
      uint4 pre[4];
      if (nsrc){
        const uint4* s4 = (const uint4*)(nsrc + w*2048);
        #pragma unroll
        for (int i = 0; i < 4; i++) pre[i] = s4[i*64 + lane];
      }
      const u16* bs = stg[u & 1];
      const int s = u - 4;
      floatx4 acc[4];
      #pragma unroll
      for (int g = 0; g < 4; g++){
        float bi = sB[512 + g*128 + s*16 + n4];
        #pragma unroll
        for (int r = 0; r < 4; r++) acc[g][r] = bi;
      }
      #pragma unroll
      for (int g = 0; g < 4; g++){
        short8 bh0 = *(const short8*)(bs + (g*4+0)*512 + lane*8);
        short8 bh1 = *(const short8*)(bs + (g*4+1)*512 + lane*8);
        short8 bh2 = *(const short8*)(bs + (g*4+2)*512 + lane*8);
        short8 bh3 = *(const short8*)(bs + (g*4+3)*512 + lane*8);
        short8 bx0 = *(const short8*)(bs + 8192 + (g*4+0)*512 + lane*8);
        short8 bx1 = *(const short8*)(bs + 8192 + (g*4+1)*512 + lane*8);
        short8 bx2 = *(const short8*)(bs + 8192 + (g*4+2)*512 + lane*8);
        short8 bx3 = *(const short8*)(bs + 8192 + (g*4+3)*512 + lane*8);
        acc[g] = __builtin_amdgcn_mfma_f32_16x16x32_bf16(a1[0], bh0, acc[g], 0,0,0);
        acc[g] = __builtin_amdgcn_mfma_f32_16x16x32_bf16(an[0], bx0, acc[g], 0,0,0);
        acc[g] = __builtin_amdgcn_mfma_f32_16x16x32_bf16(a1[1], bh1, acc[g], 0,0,0);
        acc[g] = __builtin_amdgcn_mfma_f32_16x16x32_bf16(an[1], bx1, acc[g], 0,0,0);
        acc[g] = __builtin_amdgcn_mfma_f32_16x16x32_bf16(a1[2], bh2, acc[g], 0,0,0);
        acc[g] = __builtin_amdgcn_mfma_f32_16x16x32_bf16(an[2], bx2, acc[g], 0,0,0);
        acc[g] = __builtin_amdgcn_mfma_f32_16x16x32_bf16(a1[3], bh3, acc[g], 0,0,0);
        acc[g] = __builtin_amdgcn_mfma_f32_16x16x32_bf16(an[3], bx3, acc[g], 0,0,0);
      }
      const int hb = (w*4 + (s>>1))*512 + ((s&1)*2 + (n4>>3))*128 + q*32 + (n4&7);
      floatx4 cc = c1a[s], cn;
      const float f0 = sFc[s*16 + n4], f1 = sFc[128 + s*16 + n4];
      #pragma unroll
      for (int r = 0; r < 4; r++){
        float ig = sigm2(acc[0][r]);
        float fg = sigm2(acc[1][r]);
        float gg = tanh2(acc[2][r]);
        float cv = fmaf(fg, cc[r], ig*gg);
        float og = sigm2(acc[3][r]);
        float hv = og * (1.f - 2.f*rcp_(1.f + exp2_(L2E2*cv)));
        cn[r] = cv;
        h1s[hb + r*8] = f2bf(hv);
        p[r][0] = fmaf(hv, f0, p[r][0]);
        p[r][1] = fmaf(hv, f1, p[r][1]);
      }
      c1a[s] = cn;
      if (nsrc){
        uint4* d4 = (uint4*)(stg[(u+1) & 1] + w*2048);
        #pragma unroll
        for (int i = 0; i < 4; i++) d4[i*64 + lane] = pre[i];
      }
      __syncthreads();
    }

    // ---- FC head: butterfly over n4, register feedback ----
    #pragma unroll
    for (int off = 1; off < 16; off <<= 1)
      #pragma unroll
      for (int r = 0; r < 4; r++){
        p[r][0] += __shfl_xor(p[r][0], off);
        p[r][1] += __shfl_xor(p[r][1], off);
      }
    const float fb0 = sFc[256], fb1 = sFc[257];
    #pragma unroll
    for (int r = 0; r < 4; r++){
      float2 pv; pv.x = p[r][0] + fb0; pv.y = p[r][1] + fb1;
      xc[r] = pv;
      if (n4 == 0)
        *(float2*)(out + (long)(m0 + w*16 + q*4 + r)*90 + (t - 20)*2) = pv;
    }
  }

  // ---- chunk state flush ----
  { const uint4* s0 = (const uint4*)h0s; const uint4* s1 = (const uint4*)h1s;
    uint4* d0 = (uint4*)(gH0 + hoff); uint4* d1 = (uint4*)(gH1 + hoff);
    for (int i = tid; i < 2048; i += 512){ d0[i] = s0[i]; d1[i] = s1[i]; } }
  { floatx4* pc0 = (floatx4*)gC0; floatx4* pc1 = (floatx4*)gC1;
    #pragma unroll
    for (int s = 0; s < 8; s++){ pc0[(long)s*131072 + cbase] = c0a[s]; pc1[(long)s*131072 + cbase] = c1a[s]; } }
  if (n4 == 0){
    #pragma unroll
    for (int r = 0; r < 4; r++)
      *(float2*)(gPred + (long)(m0 + w*16 + q*4 + r)*2) = xc[r];
  }
}

// ---------------- host ----------------
extern "C" void kernel_launch(void* const* d_in, const int* in_sizes, int n_in,
                              void* d_out, int out_size, void* d_ws, size_t ws_size,
                              hipStream_t stream)
{
  const float* in_seq = (const float*)d_in[0];
  const float* eWih0 = (const float*)d_in[1];
  const float* eWhh0 = (const float*)d_in[2];
  const float* ebih0 = (const float*)d_in[3];
  const float* ebhh0 = (const float*)d_in[4];
  const float* eWih1 = (const float*)d_in[5];
  const float* eWhh1 = (const float*)d_in[6];
  const float* ebih1 = (const float*)d_in[7];
  const float* ebhh1 = (const float*)d_in[8];
  const float* dWih0 = (const float*)d_in[9];
  const float* dWhh0 = (const float*)d_in[10];
  const float* dbih0 = (const float*)d_in[11];
  const float* dbhh0 = (const float*)d_in[12];
  const float* dWih1 = (const float*)d_in[13];
  const float* dWhh1 = (const float*)d_in[14];
  const float* dbih1 = (const float*)d_in[15];
  const float* dbhh1 = (const float*)d_in[16];
  const float* fcW   = (const float*)d_in[17];
  const float* fcb   = (const float*)d_in[18];
  float* out = (float*)d_out;
  char* ws = (char*)d_ws;

  u16* wE0 = (u16*)(ws + 0);                   // 128 KB
  u16* wE1 = (u16*)(ws + 131072);              // 256 KB
  u16* wD0 = (u16*)(ws + 393216);              // 128 KB
  u16* wD1 = (u16*)(ws + 524288);              // 256 KB
  float* biasAll = (float*)(ws + 786432);      // 8 KB
  float* wxAll   = (float*)(ws + 794624);      // 8 KB
  u16* gH0   = (u16*)(ws + 1048576);           // 8 MB
  u16* gH1   = (u16*)(ws + 9437184);           // 8 MB
  float* gC0 = (float*)(ws + 17825792);        // 16 MB
  float* gC1 = (float*)(ws + 34603008);        // 16 MB
  float* gPred = (float*)(ws + 51380224);      // 256 KB

  hipLaunchKernelGGL(prep_weights, dim3(1536), dim3(256), 0, stream,
                     eWhh0, eWhh1, eWih1, dWhh0, dWhh1, dWih1,
                     wE0, wE1, wD0, wD1);
  hipLaunchKernelGGL(prep_small, dim3(16), dim3(256), 0, stream,
                     ebih0, ebhh0, ebih1, ebhh1, dbih0, dbhh0, dbih1, dbhh1,
                     eWih0, dWih0, biasAll, wxAll);

  for (int t0 = 0; t0 < 20; t0 += 5)
    hipLaunchKernelGGL(enc_chunk, dim3(256), dim3(512), 0, stream,
                       in_seq, (const u16*)wE0, (const u16*)wE1,
                       (const float*)biasAll, (const float*)wxAll,
                       gH0, gH1, gC0, gC1, t0, 5);

  for (int t0 = 20; t0 < 65; t0 += 5)
    hipLaunchKernelGGL(dec_chunk, dim3(256), dim3(512), 0, stream,
                       in_seq, (const u16*)wD0, (const u16*)wD1,
                       (const float*)(biasAll + 1024), (const float*)(wxAll + 1024),
                       fcW, fcb, gH0, gH1, gC0, gC1, gPred, out,
                       t0, 5, (t0 == 20) ? 1 : 0);
}

// Round 6
// 1913.587 us; speedup vs baseline: 2.7268x; 1.0865x over previous
//
#include <hip/hip_runtime.h>

typedef unsigned int u32;
typedef unsigned short u16;
typedef __attribute__((ext_vector_type(8))) short short8;
typedef __attribute__((ext_vector_type(4))) float floatx4;

#define L2E  1.44269504088896340736f
#define L2E2 2.88539008177792681472f

static __device__ __forceinline__ u16 f2bf(float f){
  u32 u = __float_as_uint(f);
  u = (u + 0x7FFFu + ((u >> 16) & 1u)) >> 16;
  return (u16)u;
}
static __device__ __forceinline__ float rcp_(float x){ return __builtin_amdgcn_rcpf(x); }
static __device__ __forceinline__ float exp2_(float x){ return __builtin_amdgcn_exp2f(x); }
static __device__ __forceinline__ float sigm2(float yh){ return rcp_(1.f + exp2_(-yh)); }   // log2e folded
static __device__ __forceinline__ float tanh2(float yh2){ return 1.f - 2.f*rcp_(1.f + exp2_(yh2)); } // 2*log2e folded

// ---- prep: weights -> slice-major MFMA B-frag order, bf16, log2e-prescaled ----
// Hybrid layout: each 32KB ring unit = [group-A slice (16KB) | group-B slice].
// cell0 (W0hh): slice s -> unit (s&3), half (s>>2).
// cell1: Whh slice s -> unit 2*(s&3); Wih slice s -> unit 2*(s&3)+1; half (s>>2).
__global__ __launch_bounds__(256) void prep_weights(
    const float* eWhh0, const float* eWhh1, const float* eWih1,
    const float* dWhh0, const float* dWhh1, const float* dWih1,
    u16* wE0, u16* wE1, u16* wD0, u16* wD1)
{
  int idx = blockIdx.x * 256 + threadIdx.x;   // 6*65536
  int m = idx >> 16, e = idx & 65535;
  int j = e & 7, L = (e >> 3) & 63, c = (e >> 9) & 3, g = (e >> 11) & 3, s = (e >> 13) & 7;
  int row = g*128 + s*16 + (L & 15);
  int col = c*32 + ((L >> 4) * 8) + j;
  float scale = (g == 2) ? L2E2 : L2E;
  int frag = (g*4 + c)*512 + L*8 + j;
  int half = (s >> 2) * 8192, s4 = s & 3;
  const float* src; u16* dst; long off;
  switch(m){
    case 0: src = eWhh0; dst = wE0; off = (long)s4*16384        + half + frag; break;
    case 1: src = eWhh1; dst = wE1; off = (long)(2*s4)*16384    + half + frag; break;
    case 2: src = eWih1; dst = wE1; off = (long)(2*s4+1)*16384  + half + frag; break;
    case 3: src = dWhh0; dst = wD0; off = (long)s4*16384        + half + frag; break;
    case 4: src = dWhh1; dst = wD1; off = (long)(2*s4)*16384    + half + frag; break;
    default:src = dWih1; dst = wD1; off = (long)(2*s4+1)*16384  + half + frag; break;
  }
  dst[off] = f2bf(src[row*128 + col] * scale);
}

__global__ __launch_bounds__(256) void prep_small(
    const float* ebih0,const float* ebhh0,const float* ebih1,const float* ebhh1,
    const float* dbih0,const float* dbhh0,const float* dbih1,const float* dbhh1,
    const float* eWih0,const float* dWih0, float* biasAll, float* wxAll)
{
  int i = blockIdx.x*256 + threadIdx.x;    // 4096
  if (i < 2048){
    int l = i >> 9, n = i & 511, g = (n >> 7) & 3;
    const float* a = l==0?ebih0: l==1?ebih1: l==2?dbih0: dbih1;
    const float* b = l==0?ebhh0: l==1?ebhh1: l==2?dbhh0: dbhh1;
    biasAll[i] = (a[n] + b[n]) * ((g==2)? L2E2 : L2E);
  } else {
    int k = i - 2048;                       // 2 x 1024
    int l = k >> 10, e2 = k & 1023, n = e2 >> 1, g = (n >> 7) & 3;
    const float* wsrc = l ? dWih0 : eWih0;
    wxAll[k] = wsrc[e2] * ((g==2)? L2E2 : L2E);
  }
}

// =======================================================================
// Hybrid step: 8 waves = 4 M-pairs x 2 N-halves. Wave w: grp = w>>2 (unit
// half [grp*64, grp*64+64)), mtiles mtb=(w&3)*2, mtb+1 (32 samples). Ring
// unchanged (12 units/step, 2x32KB, parity u&1, barrier per unit); wave
// consumes its 16KB half of each unit, reusing each B-frag for 2 mtiles.
// Cross-group h handoff: ah regs refreshed from h0s only after the u3
// barrier (all h0 writes pre-barrier); a1 read at step top (h1 writes are
// post-u3, ordered by u0..u3 barriers). FC partials cross groups via fcp
// scratch written before / read after the u11 barrier.
// =======================================================================
template<bool DEC>
static __device__ __forceinline__ void step_h(
    int w, int grp, int mtb, int lane, int n4, int q, int m0, int t,
    u16* h0s, u16* h1s, u16 (*stg)[16384], float* fcp,
    const float* sB, const float* sWx, const float* sFc,
    const u16* w0b, const u16* w1b, const u16* nx0,
    short8 (&ah)[2][4], float2 (&xc)[2][4],
    floatx4 (&c0a)[2][4], floatx4 (&c1a)[2][4],
    float* __restrict__ out)
{
  const int grpo = grp * 8192;
  // h1_old A-frags (own 2 mtiles, full K): safe here — first h1 write of this
  // step is after the u3 barrier.
  short8 a1[2][4];
  #pragma unroll
  for (int j = 0; j < 2; j++)
    #pragma unroll
    for (int c = 0; c < 4; c++)
      a1[j][c] = *(const short8*)(h1s + ((mtb+j)*4 + c)*512 + lane*8);

  // ---------------- cell 0: units 0..3, one slice (own half) per unit ------
  #pragma unroll 1
  for (int u = 0; u < 4; u++){
    const u16* nsrc = (u < 3) ? (w0b + (u+1)*16384) : w1b;
    uint4 pre[4];
    { const uint4* s4 = (const uint4*)(nsrc + w*2048);
      #pragma unroll
      for (int i = 0; i < 4; i++) pre[i] = s4[i*64 + lane]; }
    const u16* bs = stg[u & 1] + grpo;
    const int s = u + grp*4;
    floatx4 acc[4][2];
    #pragma unroll
    for (int g = 0; g < 4; g++){
      float bi = sB[g*128 + s*16 + n4];
      float2 wv = *(const float2*)(sWx + (g*128 + s*16 + n4)*2);
      #pragma unroll
      for (int j = 0; j < 2; j++)
        #pragma unroll
        for (int r = 0; r < 4; r++)
          acc[g][j][r] = fmaf(xc[j][r].y, wv.y, fmaf(xc[j][r].x, wv.x, bi));
    }
    #pragma unroll
    for (int c = 0; c < 4; c++)
      #pragma unroll
      for (int g = 0; g < 4; g++){
        short8 b = *(const short8*)(bs + (g*4 + c)*512 + lane*8);
        acc[g][0] = __builtin_amdgcn_mfma_f32_16x16x32_bf16(ah[0][c], b, acc[g][0], 0,0,0);
        acc[g][1] = __builtin_amdgcn_mfma_f32_16x16x32_bf16(ah[1][c], b, acc[g][1], 0,0,0);
      }
    #pragma unroll
    for (int j = 0; j < 2; j++){
      const int hb = ((mtb+j)*4 + (s>>1))*512 + ((s&1)*2 + (n4>>3))*128 + q*32 + (n4&7);
      floatx4 cc = c0a[j][u], cn;
      #pragma unroll
      for (int r = 0; r < 4; r++){
        float ig = sigm2(acc[0][j][r]);
        float fg = sigm2(acc[1][j][r]);
        float gg = tanh2(acc[2][j][r]);
        float cv = fmaf(fg, cc[r], ig*gg);
        float og = sigm2(acc[3][j][r]);
        float hv = og * (1.f - 2.f*rcp_(1.f + exp2_(L2E2*cv)));
        cn[r] = cv;
        h0s[hb + r*8] = f2bf(hv);
      }
      c0a[j][u] = cn;
    }
    { uint4* d4 = (uint4*)(stg[(u+1) & 1] + w*2048);
      #pragma unroll
      for (int i = 0; i < 4; i++) d4[i*64 + lane] = pre[i]; }
    __syncthreads();
  }

  // refresh ah = h0_new (all h0 writes completed before the u3 barrier);
  // these regs also serve as next step's h0_old frags.
  #pragma unroll
  for (int j = 0; j < 2; j++)
    #pragma unroll
    for (int c = 0; c < 4; c++)
      ah[j][c] = *(const short8*)(h0s + ((mtb+j)*4 + c)*512 + lane*8);

  float p[2][4][2];
  if (DEC){
    #pragma unroll
    for (int j = 0; j < 2; j++)
      #pragma unroll
      for (int r = 0; r < 4; r++){ p[j][r][0] = 0.f; p[j][r][1] = 0.f; }
  }

  // ---------------- cell 1: slice i, units 4+2i (Whh x a1), 5+2i (Wih x h0new)
  #pragma unroll 1
  for (int i = 0; i < 4; i++){
    const int s = i + grp*4;
    floatx4 acc[4][2];
    {
      const int u = 4 + 2*i;
      const u16* nsrc = w1b + (u-3)*16384;
      uint4 pre[4];
      { const uint4* s4 = (const uint4*)(nsrc + w*2048);
        #pragma unroll
        for (int k = 0; k < 4; k++) pre[k] = s4[k*64 + lane]; }
      const u16* bs = stg[u & 1] + grpo;
      #pragma unroll
      for (int g = 0; g < 4; g++){
        float bi = sB[512 + g*128 + s*16 + n4];
        #pragma unroll
        for (int j = 0; j < 2; j++)
          #pragma unroll
          for (int r = 0; r < 4; r++) acc[g][j][r] = bi;
      }
      #pragma unroll
      for (int c = 0; c < 4; c++)
        #pragma unroll
        for (int g = 0; g < 4; g++){
          short8 bh = *(const short8*)(bs + (g*4 + c)*512 + lane*8);
          acc[g][0] = __builtin_amdgcn_mfma_f32_16x16x32_bf16(a1[0][c], bh, acc[g][0], 0,0,0);
          acc[g][1] = __builtin_amdgcn_mfma_f32_16x16x32_bf16(a1[1][c], bh, acc[g][1], 0,0,0);
        }
      { uint4* d4 = (uint4*)(stg[(u+1) & 1] + w*2048);
        #pragma unroll
        for (int k = 0; k < 4; k++) d4[k*64 + lane] = pre[k]; }
      __syncthreads();
    }
    {
      const int u = 5 + 2*i;
      const u16* nsrc = (u < 11) ? (w1b + (u-3)*16384) : nx0;
      uint4 pre[4];
      if (nsrc){
        const uint4* s4 = (const uint4*)(nsrc + w*2048);
        #pragma unroll
        for (int k = 0; k < 4; k++) pre[k] = s4[k*64 + lane];
      }
      const u16* bs = stg[u & 1] + grpo;
      #pragma unroll
      for (int c = 0; c < 4; c++)
        #pragma unroll
        for (int g = 0; g < 4; g++){
          short8 bx = *(const short8*)(bs + (g*4 + c)*512 + lane*8);
          acc[g][0] = __builtin_amdgcn_mfma_f32_16x16x32_bf16(ah[0][c], bx, acc[g][0], 0,0,0);
          acc[g][1] = __builtin_amdgcn_mfma_f32_16x16x32_bf16(ah[1][c], bx, acc[g][1], 0,0,0);
        }
      float f0 = 0.f, f1 = 0.f;
      if (DEC){ f0 = sFc[s*16 + n4]; f1 = sFc[128 + s*16 + n4]; }
      #pragma unroll
      for (int j = 0; j < 2; j++){
        const int hb = ((mtb+j)*4 + (s>>1))*512 + ((s&1)*2 + (n4>>3))*128 + q*32 + (n4&7);
        floatx4 cc = c1a[j][i], cn;
        #pragma unroll
        for (int r = 0; r < 4; r++){
          float ig = sigm2(acc[0][j][r]);
          float fg = sigm2(acc[1][j][r]);
          float gg = tanh2(acc[2][j][r]);
          float cv = fmaf(fg, cc[r], ig*gg);
          float og = sigm2(acc[3][j][r]);
          float hv = og * (1.f - 2.f*rcp_(1.f + exp2_(L2E2*cv)));
          cn[r] = cv;
          h1s[hb + r*8] = f2bf(hv);
          if (DEC){
            p[j][r][0] = fmaf(hv, f0, p[j][r][0]);
            p[j][r][1] = fmaf(hv, f1, p[j][r][1]);
          }
        }
        c1a[j][i] = cn;
      }
      if (DEC && i == 3){
        // butterfly over n4 (16 lanes) -> per-group partial; stash pre-barrier
        #pragma unroll
        for (int off = 1; off < 16; off <<= 1)
          #pragma unroll
          for (int j = 0; j < 2; j++)
            #pragma unroll
            for (int r = 0; r < 4; r++){
              p[j][r][0] += __shfl_xor(p[j][r][0], off);
              p[j][r][1] += __shfl_xor(p[j][r][1], off);
            }
        if (n4 == 0){
          #pragma unroll
          for (int j = 0; j < 2; j++)
            #pragma unroll
            for (int r = 0; r < 4; r++){
              const int base = ((mtb+j)*16 + q*4 + r)*4 + grp*2;
              fcp[base + 0] = p[j][r][0];
              fcp[base + 1] = p[j][r][1];
            }
        }
      }
      if (nsrc){
        uint4* d4 = (uint4*)(stg[(u+1) & 1] + w*2048);
        #pragma unroll
        for (int k = 0; k < 4; k++) d4[k*64 + lane] = pre[k];
      }
      __syncthreads();
    }
  }

  if (DEC){
    const float fb0 = sFc[256], fb1 = sFc[257];
    #pragma unroll
    for (int j = 0; j < 2; j++)
      #pragma unroll
      for (int r = 0; r < 4; r++){
        const int base = ((mtb+j)*16 + q*4 + r)*4;
        float2 pv;
        pv.x = fcp[base + 0] + fcp[base + 2] + fb0;
        pv.y = fcp[base + 1] + fcp[base + 3] + fb1;
        xc[j][r] = pv;
        if (grp == 0 && n4 == 0)
          *(float2*)(out + (long)(m0 + (mtb+j)*16 + q*4 + r)*90 + (t - 20)*2) = pv;
      }
  }
}

__global__ __launch_bounds__(512, 1) void enc_chunk(
    const float* __restrict__ in_seq,
    const u16* __restrict__ wE0, const u16* __restrict__ wE1,
    const float* __restrict__ biasAll, const float* __restrict__ wxAll,
    u16* __restrict__ gH0, u16* __restrict__ gH1,
    float* __restrict__ gC0, float* __restrict__ gC1,
    int t0, int K)
{
  __shared__ u16 h0s[16384];
  __shared__ u16 h1s[16384];
  __shared__ u16 stg[2][16384];
  __shared__ float sB[1024];
  __shared__ float sWx[1024];
  __shared__ float fcp[512];

  const int tid = threadIdx.x, lane = tid & 63, w = tid >> 6;
  const int grp = w >> 2, mtb = (w & 3) * 2;
  const int n4 = lane & 15, q = lane >> 4;
  const int m0 = blockIdx.x * 128;
  const long hoff = (long)blockIdx.x * 16384;
  const long cbase = (long)blockIdx.x * 512 + tid;

  for (int i = tid; i < 1024; i += 512){ sB[i] = biasAll[i]; sWx[i] = wxAll[i]; }

  floatx4 c0a[2][4], c1a[2][4];
  if (t0 == 0){
    u32* z0 = (u32*)h0s; u32* z1 = (u32*)h1s;
    for (int i = tid; i < 8192; i += 512){ z0[i] = 0u; z1[i] = 0u; }
    const floatx4 z4 = {0.f,0.f,0.f,0.f};
    #pragma unroll
    for (int j = 0; j < 2; j++)
      #pragma unroll
      for (int i = 0; i < 4; i++){ c0a[j][i] = z4; c1a[j][i] = z4; }
  } else {
    uint4* d0 = (uint4*)h0s; uint4* d1 = (uint4*)h1s;
    const uint4* s0 = (const uint4*)(gH0 + hoff);
    const uint4* s1 = (const uint4*)(gH1 + hoff);
    for (int i = tid; i < 2048; i += 512){ d0[i] = s0[i]; d1[i] = s1[i]; }
    const floatx4* pc0 = (const floatx4*)gC0;
    const floatx4* pc1 = (const floatx4*)gC1;
    #pragma unroll
    for (int j = 0; j < 2; j++)
      #pragma unroll
      for (int i = 0; i < 4; i++){
        c0a[j][i] = pc0[(long)(j*4+i)*131072 + cbase];
        c1a[j][i] = pc1[(long)(j*4+i)*131072 + cbase];
      }
  }
  { const uint4* s4 = (const uint4*)(wE0 + w*2048);
    uint4* d4 = (uint4*)(stg[0] + w*2048);
    #pragma unroll
    for (int i = 0; i < 4; i++) d4[i*64 + lane] = s4[i*64 + lane]; }
  __syncthreads();

  // prime h0_old frags; extra barrier orders these reads before step-0 writes
  short8 ah[2][4];
  #pragma unroll
  for (int j = 0; j < 2; j++)
    #pragma unroll
    for (int c = 0; c < 4; c++)
      ah[j][c] = *(const short8*)(h0s + ((mtb+j)*4 + c)*512 + lane*8);
  __syncthreads();

  float2 xc[2][4];
  #pragma unroll 1
  for (int tt = 0; tt < K; tt++){
    const int t = t0 + tt;
    #pragma unroll
    for (int j = 0; j < 2; j++)
      #pragma unroll
      for (int r = 0; r < 4; r++)
        xc[j][r] = *(const float2*)(in_seq + (long)(m0 + (mtb+j)*16 + q*4 + r)*40 + t*2);
    step_h<false>(w, grp, mtb, lane, n4, q, m0, t, h0s, h1s, stg, fcp,
                  sB, sWx, (const float*)nullptr,
                  wE0, wE1, (tt < K-1) ? wE0 : (const u16*)nullptr,
                  ah, xc, c0a, c1a, (float*)nullptr);
  }

  { const uint4* s0 = (const uint4*)h0s; const uint4* s1 = (const uint4*)h1s;
    uint4* d0 = (uint4*)(gH0 + hoff); uint4* d1 = (uint4*)(gH1 + hoff);
    for (int i = tid; i < 2048; i += 512){ d0[i] = s0[i]; d1[i] = s1[i]; } }
  { floatx4* pc0 = (floatx4*)gC0; floatx4* pc1 = (floatx4*)gC1;
    #pragma unroll
    for (int j = 0; j < 2; j++)
      #pragma unroll
      for (int i = 0; i < 4; i++){
        pc0[(long)(j*4+i)*131072 + cbase] = c0a[j][i];
        pc1[(long)(j*4+i)*131072 + cbase] = c1a[j][i];
      } }
}

__global__ __launch_bounds__(512, 1) void dec_chunk(
    const float* __restrict__ in_seq,
    const u16* __restrict__ wD0, const u16* __restrict__ wD1,
    const float* __restrict__ biasD, const float* __restrict__ wxD,
    const float* __restrict__ fcW, const float* __restrict__ fcb,
    u16* __restrict__ gH0, u16* __restrict__ gH1,
    float* __restrict__ gC0, float* __restrict__ gC1,
    float* __restrict__ gPred, float* __restrict__ out,
    int t0, int K, int first)
{
  __shared__ u16 h0s[16384];
  __shared__ u16 h1s[16384];
  __shared__ u16 stg[2][16384];
  __shared__ float sB[1024];
  __shared__ float sWx[1024];
  __shared__ float sFc[260];
  __shared__ float fcp[512];

  const int tid = threadIdx.x, lane = tid & 63, w = tid >> 6;
  const int grp = w >> 2, mtb = (w & 3) * 2;
  const int n4 = lane & 15, q = lane >> 4;
  const int m0 = blockIdx.x * 128;
  const long hoff = (long)blockIdx.x * 16384;
  const long cbase = (long)blockIdx.x * 512 + tid;

  for (int i = tid; i < 1024; i += 512){ sB[i] = biasD[i]; sWx[i] = wxD[i]; }
  if (tid < 258) sFc[tid] = (tid < 256) ? fcW[tid] : fcb[tid-256];

  floatx4 c0a[2][4], c1a[2][4];
  { uint4* d0 = (uint4*)h0s; uint4* d1 = (uint4*)h1s;
    const uint4* s0 = (const uint4*)(gH0 + hoff);
    const uint4* s1 = (const uint4*)(gH1 + hoff);
    for (int i = tid; i < 2048; i += 512){ d0[i] = s0[i]; d1[i] = s1[i]; }
    const floatx4* pc0 = (const floatx4*)gC0;
    const floatx4* pc1 = (const floatx4*)gC1;
    #pragma unroll
    for (int j = 0; j < 2; j++)
      #pragma unroll
      for (int i = 0; i < 4; i++){
        c0a[j][i] = pc0[(long)(j*4+i)*131072 + cbase];
        c1a[j][i] = pc1[(long)(j*4+i)*131072 + cbase];
      } }
  { const uint4* s4 = (const uint4*)(wD0 + w*2048);
    uint4* d4 = (uint4*)(stg[0] + w*2048);
    #pragma unroll
    for (int i = 0; i < 4; i++) d4[i*64 + lane] = s4[i*64 + lane]; }

  float2 xc[2][4];
  #pragma unroll
  for (int j = 0; j < 2; j++)
    #pragma unroll
    for (int r = 0; r < 4; r++){
      const long mm = m0 + (mtb+j)*16 + q*4 + r;
      xc[j][r] = first ? *(const float2*)(in_seq + mm*40 + 38)
                       : *(const float2*)(gPred + mm*2);
    }
  __syncthreads();

  short8 ah[2][4];
  #pragma unroll
  for (int j = 0; j < 2; j++)
    #pragma unroll
    for (int c = 0; c < 4; c++)
      ah[j][c] = *(const short8*)(h0s + ((mtb+j)*4 + c)*512 + lane*8);
  __syncthreads();

  #pragma unroll 1
  for (int tt = 0; tt < K; tt++){
    const int t = t0 + tt;
    step_h<true>(w, grp, mtb, lane, n4, q, m0, t, h0s, h1s, stg, fcp,
                 sB, sWx, sFc,
                 wD0, wD1, (tt < K-1) ? wD0 : (const u16*)nullptr,
                 ah, xc, c0a, c1a, out);
  }

  { const uint4* s0 = (const uint4*)h0s; const uint4* s1 = (const uint4*)h1s;
    uint4* d0 = (uint4*)(gH0 + hoff); uint4* d1 = (uint4*)(gH1 + hoff);
    for (int i = tid; i < 2048; i += 512){ d0[i] = s0[i]; d1[i] = s1[i]; } }
  { floatx4* pc0 = (floatx4*)gC0; floatx4* pc1 = (floatx4*)gC1;
    #pragma unroll
    for (int j = 0; j < 2; j++)
      #pragma unroll
      for (int i = 0; i < 4; i++){
        pc0[(long)(j*4+i)*131072 + cbase] = c0a[j][i];
        pc1[(long)(j*4+i)*131072 + cbase] = c1a[j][i];
      } }
  if (grp == 0 && n4 == 0){
    #pragma unroll
    for (int j = 0; j < 2; j++)
      #pragma unroll
      for (int r = 0; r < 4; r++)
        *(float2*)(gPred + (long)(m0 + (mtb+j)*16 + q*4 + r)*2) = xc[j][r];
  }
}

// ---------------- host ----------------
extern "C" void kernel_launch(void* const* d_in, const int* in_sizes, int n_in,
                              void* d_out, int out_size, void* d_ws, size_t ws_size,
                              hipStream_t stream)
{
  const float* in_seq = (const float*)d_in[0];
  const float* eWih0 = (const float*)d_in[1];
  const float* eWhh0 = (const float*)d_in[2];
  const float* ebih0 = (const float*)d_in[3];
  const float* ebhh0 = (const float*)d_in[4];
  const float* eWih1 = (const float*)d_in[5];
  const float* eWhh1 = (const float*)d_in[6];
  const float* ebih1 = (const float*)d_in[7];
  const float* ebhh1 = (const float*)d_in[8];
  const float* dWih0 = (const float*)d_in[9];
  const float* dWhh0 = (const float*)d_in[10];
  const float* dbih0 = (const float*)d_in[11];
  const float* dbhh0 = (const float*)d_in[12];
  const float* dWih1 = (const float*)d_in[13];
  const float* dWhh1 = (const float*)d_in[14];
  const float* dbih1 = (const float*)d_in[15];
  const float* dbhh1 = (const float*)d_in[16];
  const float* fcW   = (const float*)d_in[17];
  const float* fcb   = (const float*)d_in[18];
  float* out = (float*)d_out;
  char* ws = (char*)d_ws;

  u16* wE0 = (u16*)(ws + 0);                   // 128 KB
  u16* wE1 = (u16*)(ws + 131072);              // 256 KB
  u16* wD0 = (u16*)(ws + 393216);              // 128 KB
  u16* wD1 = (u16*)(ws + 524288);              // 256 KB
  float* biasAll = (float*)(ws + 786432);      // 8 KB
  float* wxAll   = (float*)(ws + 794624);      // 8 KB
  u16* gH0   = (u16*)(ws + 1048576);           // 8 MB
  u16* gH1   = (u16*)(ws + 9437184);           // 8 MB
  float* gC0 = (float*)(ws + 17825792);        // 16 MB
  float* gC1 = (float*)(ws + 34603008);        // 16 MB
  float* gPred = (float*)(ws + 51380224);      // 256 KB

  hipLaunchKernelGGL(prep_weights, dim3(1536), dim3(256), 0, stream,
                     eWhh0, eWhh1, eWih1, dWhh0, dWhh1, dWih1,
                     wE0, wE1, wD0, wD1);
  hipLaunchKernelGGL(prep_small, dim3(16), dim3(256), 0, stream,
                     ebih0, ebhh0, ebih1, ebhh1, dbih0, dbhh0, dbih1, dbhh1,
                     eWih0, dWih0, biasAll, wxAll);

  for (int t0 = 0; t0 < 20; t0 += 10)
    hipLaunchKernelGGL(enc_chunk, dim3(256), dim3(512), 0, stream,
                       in_seq, (const u16*)wE0, (const u16*)wE1,
                       (const float*)biasAll, (const float*)wxAll,
                       gH0, gH1, gC0, gC1, t0, 10);

  for (int t0 = 20; t0 < 65; t0 += 9)
    hipLaunchKernelGGL(dec_chunk, dim3(256), dim3(512), 0, stream,
                       in_seq, (const u16*)wD0, (const u16*)wD1,
                       (const float*)(biasAll + 1024), (const float*)(wxAll + 1024),
                       fcW, fcb, gH0, gH1, gC0, gC1, gPred, out,
                       t0, 9, (t0 == 20) ? 1 : 0);
}